// Round 1
// baseline (1956.813 us; speedup 1.0000x reference)
//
#include <hip/hip_runtime.h>
#include <hip/hip_bf16.h>
#include <stdint.h>

// ---------------------------------------------------------------------------
// BasisCustBiLSTM: per-sample basis-mixed BiLSTM.
//   k_meta / k_xbf / k_whhp / k_bias / k_mixwih / k_gemm : prep (unchanged)
//   k_hinit: zeroes the h exchange buffers + flags through the MALL (sc0 sc1)
//     so k_recur can use monotone >= flag polling (re-launch safe via kernel
//     boundary, no in-kernel init races).
//   k_recur R6: decoupled readiness/payload exchange.
//     R5 polled 16B tagged records = the full 64 KB state per block per poll
//     round (~16 MB MALL traffic/round system-wide) -> poll-BW-bound at
//     5.5 us/step. R6: raw h payload hdat[dir][buf][kb=ch/8][sample][16B]
//     (32 KB per dir-buf, full-line coalesced, loaded ONCE per step) gated by
//     128 packed u32 flags per dir (512 B broadcast poll per wave per round).
//     Producer: store h -> vmcnt(0) -> store flag[wg]=t+1. Reader: poll
//     flags >= t, then one bulk load. Overwrite safety: producer writes
//     buf[t&1] for step t+2 only after observing all flags >= t+1, which
//     requires every block to have completed step-t reads (R5's transitive
//     argument, unchanged).
//     Wave roles: w0-1 prefetch+cell, w2 out-store, w3 h publish.
// ---------------------------------------------------------------------------

typedef __attribute__((ext_vector_type(8))) __bf16 bf16x8;
typedef __attribute__((ext_vector_type(4))) __bf16 bf16x4;
typedef __attribute__((ext_vector_type(4))) float  f32x4;
typedef __attribute__((ext_vector_type(4))) unsigned u32x4;
typedef __attribute__((ext_vector_type(2))) unsigned u32x2;

#define TT 256
#define BBATCH 32

__device__ __forceinline__ __bf16 f2bf(float f){
  unsigned u = __builtin_bit_cast(unsigned, f);
  unsigned short r = (unsigned short)((u + 0x7fffu + ((u >> 16) & 1u)) >> 16);
  return __builtin_bit_cast(__bf16, r);
}
__device__ __forceinline__ float sigm(float x){
  x = fminf(fmaxf(x, -30.f), 30.f);
  return 1.f / (1.f + __expf(-x));
}
__device__ __forceinline__ float tanh_(float x){
  x = fminf(fmaxf(x, -15.f), 15.f);
  float e = __expf(2.f * x);
  return (e - 1.f) / (e + 1.f);
}

// --- coherent (MALL-level) access helpers: sc0 sc1 = bypass L1+L2 ----------
__device__ __forceinline__ u32x4 ld_b128_coh(const void* p){
  u32x4 v;
  asm volatile("global_load_dwordx4 %0, %1, off sc0 sc1"
               : "=v"(v) : "v"(p) : "memory");
  return v;
}
__device__ __forceinline__ u32x2 ld_b64_coh(const void* p){
  u32x2 v;
  asm volatile("global_load_dwordx2 %0, %1, off sc0 sc1"
               : "=v"(v) : "v"(p) : "memory");
  return v;
}
__device__ __forceinline__ void st_b128_coh(void* p, u32x4 v){
  asm volatile("global_store_dwordx4 %0, %1, off sc0 sc1"
               :: "v"(p), "v"(v) : "memory");
}
__device__ __forceinline__ void st_b64_coh(void* p, u32x2 v){
  asm volatile("global_store_dwordx2 %0, %1, off sc0 sc1"
               :: "v"(p), "v"(v) : "memory");
}
__device__ __forceinline__ void st_b32_coh(void* p, unsigned v){
  asm volatile("global_store_dword %0, %1, off sc0 sc1"
               :: "v"(p), "v"(v) : "memory");
}

// ---------------------------------------------------------------------------
__global__ void k_meta(const void* __restrict__ mask,
                       const int* __restrict__ meta_a, const int* __restrict__ meta_c,
                       const float* __restrict__ emb_a, const float* __restrict__ emb_c,
                       const float* __restrict__ W1, const float* __restrict__ b1,
                       const float* __restrict__ W2,
                       float* __restrict__ c_out, int* __restrict__ len_out)
{
  __shared__ int s_bad;
  __shared__ float q_sh[32][128];
  __shared__ float hid[32][64];
  const int tid = threadIdx.x;
  if (tid == 0) s_bad = 0;
  __syncthreads();

  if (tid < 32){
    const unsigned char* m8 = (const unsigned char*)mask;
    int cnt = 0, seen0 = 0, bad = 0;
    for (int t = 0; t < TT; ++t){
      unsigned char v = m8[tid * TT + t];
      if (v > 1) bad = 1;
      if (v){ if (seen0) bad = 1; cnt++; } else seen0 = 1;
    }
    if (tid == 0 && cnt != TT) bad = 1;
    if (bad) atomicAdd(&s_bad, 1);
    len_out[tid] = cnt;
  }
  {
    int b = tid >> 3, p = tid & 7;
    int a = meta_a[b], c = meta_c[b];
    for (int i = 0; i < 16; ++i){
      int qi = p * 16 + i;
      q_sh[b][qi] = (qi < 64) ? emb_a[a * 64 + qi] : emb_c[c * 64 + (qi - 64)];
    }
  }
  __syncthreads();
  if (s_bad){
    if (tid < 32){
      const int* m32 = (const int*)mask;
      int cnt = 0;
      for (int t = 0; t < TT; ++t) if (m32[tid * TT + t]) cnt++;
      len_out[tid] = cnt;
    }
  }
  {
    int b = tid >> 3, kg = tid & 7;
    for (int k8 = 0; k8 < 8; ++k8){
      int k = kg * 8 + k8;
      float s = b1[k];
      for (int i = 0; i < 128; ++i) s += q_sh[b][i] * W1[i * 64 + k];
      hid[b][k] = tanhf(s);
    }
  }
  __syncthreads();
  if (tid < 32){
    float lg[8]; float mx = -1e30f;
    for (int n = 0; n < 8; ++n){
      float s = 0.f;
      for (int k = 0; k < 64; ++k) s += hid[tid][k] * W2[k * 8 + n];
      lg[n] = s; mx = fmaxf(mx, s);
    }
    float den = 0.f;
    for (int n = 0; n < 8; ++n){ lg[n] = expf(lg[n] - mx); den += lg[n]; }
    for (int n = 0; n < 8; ++n) c_out[tid * 8 + n] = lg[n] / den;
  }
}

// ---------------------------------------------------------------------------
// zero the h exchange region (2 dir x 2 buf x 32 KB data + 1 KB flags)
// through the MALL so monotone >= flag polling is re-launch safe.
__global__ void k_hinit(u32x4* hx)
{
  int i = blockIdx.x * 256 + threadIdx.x;
  if (i >= 8256) return;            // 8256 * 16 B = 132096 B
  u32x4 z = {0u, 0u, 0u, 0u};
  st_b128_coh(hx + i, z);
  asm volatile("s_waitcnt vmcnt(0)" ::: "memory");
}

// ---------------------------------------------------------------------------
__global__ void k_xbf(const float* __restrict__ x, __bf16* __restrict__ xb)
{
  int i = blockIdx.x * 256 + threadIdx.x;
  if (i >= 524288) return;
  f32x4 a = *(const f32x4*)(x + (size_t)i * 8);
  f32x4 b = *(const f32x4*)(x + (size_t)i * 8 + 4);
  bf16x8 o;
  #pragma unroll
  for (int j = 0; j < 4; ++j){ o[j] = f2bf(a[j]); o[4 + j] = f2bf(b[j]); }
  *(bf16x8*)(xb + (size_t)i * 8) = o;
}

// ---------------------------------------------------------------------------
__global__ void k_whhp(const float* __restrict__ whh_f, const float* __restrict__ whh_r,
                       __bf16* __restrict__ outp)
{
  int idx = blockIdx.x * 256 + threadIdx.x;
  int lane = idx & 63; int grp = idx >> 6;
  int n  = grp & 7;  grp >>= 3;
  int kt = grp & 3;  grp >>= 2;
  int wv = grp & 3;  grp >>= 2;
  int wg = grp & 127; int dir = (grp >> 7) & 1;
  int col = lane & 15, quad = lane >> 4;
  int gate = col >> 2, jj = col & 3;
  int g = gate * 512 + wg * 4 + jj;
  int k = (wv * 4 + kt) * 32 + quad * 8;
  const float* Wb = dir ? whh_r : whh_f;
  const float* s = Wb + ((size_t)n * 2048 + g) * 512 + k;
  f32x4 a = *(const f32x4*)s, b = *(const f32x4*)(s + 4);
  bf16x8 o;
  #pragma unroll
  for (int j = 0; j < 4; ++j){ o[j] = f2bf(a[j]); o[4 + j] = f2bf(b[j]); }
  *(bf16x8*)(outp + (size_t)idx * 8) = o;
}

// ---------------------------------------------------------------------------
__global__ void k_bias(const float* __restrict__ b_f, const float* __restrict__ b_r,
                       const float* __restrict__ cb, float* __restrict__ bm)
{
  int idx = blockIdx.x * 256 + threadIdx.x;
  int dir = idx >> 16; int b = (idx >> 11) & 31; int g = idx & 2047;
  const float* bb = dir ? b_r : b_f;
  float s = 0.f;
  #pragma unroll
  for (int n = 0; n < 8; ++n) s += cb[b * 8 + n] * bb[n * 2048 + g];
  bm[idx] = s;
}

// ---------------------------------------------------------------------------
__global__ void k_mixwih(const float* __restrict__ Wb, const float* __restrict__ cb,
                         __bf16* __restrict__ wmix)
{
  __shared__ float cs[256];
  int tid = threadIdx.x;
  cs[tid] = cb[tid];
  __syncthreads();
  int idx = blockIdx.x * 256 + tid;
  int g = idx >> 6, k8 = idx & 63;
  float src[8][8];
  #pragma unroll
  for (int n = 0; n < 8; ++n){
    const float* p = Wb + ((size_t)n * 2048 + g) * 512 + k8 * 8;
    f32x4 lo = *(const f32x4*)p, hi = *(const f32x4*)(p + 4);
    #pragma unroll
    for (int j = 0; j < 4; ++j){ src[n][j] = lo[j]; src[n][4 + j] = hi[j]; }
  }
  for (int b = 0; b < 32; ++b){
    float acc[8] = {0,0,0,0,0,0,0,0};
    #pragma unroll
    for (int n = 0; n < 8; ++n){
      float cn = cs[b * 8 + n];
      #pragma unroll
      for (int j = 0; j < 8; ++j) acc[j] += cn * src[n][j];
    }
    bf16x8 o;
    #pragma unroll
    for (int j = 0; j < 8; ++j) o[j] = f2bf(acc[j]);
    *(bf16x8*)(wmix + ((size_t)b * 2048 + g) * 512 + k8 * 8) = o;
  }
}

// ---------------------------------------------------------------------------
__global__ __launch_bounds__(256) void k_gemm(const __bf16* __restrict__ xb,
                                              const __bf16* __restrict__ wmix,
                                              float* __restrict__ xp)
{
  __shared__ __bf16 As[128][72];
  __shared__ __bf16 Bs[128][72];
  const int tid = threadIdx.x, lane = tid & 63, wv = tid >> 6;
  const int quad = lane >> 4, c16 = lane & 15;
  const int wm_ = wv >> 1, wn_ = wv & 1;
  const int b = blockIdx.x >> 5, tile = blockIdx.x & 31;
  const int m0 = (tile >> 4) * 128, n0 = (tile & 15) * 128;
  const __bf16* Ap = xb + (size_t)b * TT * 512;
  const __bf16* Bp = wmix + (size_t)b * 2048 * 512;
  float* Cp = xp + (size_t)b * TT * 2048;

  f32x4 acc[4][4];
  #pragma unroll
  for (int i = 0; i < 4; ++i)
    #pragma unroll
    for (int j = 0; j < 4; ++j) acc[i][j] = (f32x4){0,0,0,0};

  for (int k0 = 0; k0 < 512; k0 += 64){
    __syncthreads();
    #pragma unroll
    for (int it = 0; it < 4; ++it){
      int r = it * 32 + (tid >> 3), c = (tid & 7) * 8;
      *(bf16x8*)&As[r][c] = *(const bf16x8*)(Ap + (size_t)(m0 + r) * 512 + k0 + c);
      *(bf16x8*)&Bs[r][c] = *(const bf16x8*)(Bp + (size_t)(n0 + r) * 512 + k0 + c);
    }
    __syncthreads();
    #pragma unroll
    for (int kt = 0; kt < 2; ++kt){
      bf16x8 af[4], bfr[4];
      #pragma unroll
      for (int i = 0; i < 4; ++i){
        af[i]  = *(const bf16x8*)&As[wm_ * 64 + i * 16 + c16][kt * 32 + quad * 8];
        bfr[i] = *(const bf16x8*)&Bs[wn_ * 64 + i * 16 + c16][kt * 32 + quad * 8];
      }
      #pragma unroll
      for (int i = 0; i < 4; ++i)
        #pragma unroll
        for (int j = 0; j < 4; ++j)
          acc[i][j] = __builtin_amdgcn_mfma_f32_16x16x32_bf16(af[i], bfr[j], acc[i][j], 0, 0, 0);
    }
  }
  #pragma unroll
  for (int i = 0; i < 4; ++i)
    #pragma unroll
    for (int j = 0; j < 4; ++j){
      int colg = n0 + wn_ * 64 + j * 16 + c16;
      #pragma unroll
      for (int r = 0; r < 4; ++r){
        int row = m0 + wm_ * 64 + i * 16 + quad * 4 + r;
        Cp[(size_t)row * 2048 + colg] = acc[i][j][r];
      }
    }
}

// ---------------------------------------------------------------------------
// k_recur R6.
//  hxch layout (all accessed sc0 sc1, MALL-coherent):
//    hdat[dir][buf][kb=0..63][sample=0..31][16 B]   4 x 32768 B @ offset 0
//      chunk (kb,sample) = h channels kb*8 .. kb*8+7 of sample, bf16.
//    hflag[dir][wg=0..127] u32                      1024 B     @ offset 131072
//      flag[wg] == v  <=>  wg's slice of h(v) is visible in buf[v&1].
//  Producer (wave 3): store 32 x 8 B h slices -> s_waitcnt vmcnt(0) ->
//    store flag[wg] = t+1. Reader: poll all 128 flags >= t (one dwordx2 per
//    lane, 512 B per wave per round), then bulk-load its 32 KB state once
//    (8 x dwordx4 per lane, 256-B contiguous per quad group).
//  Monotone >= polling is safe because k_hinit zeroed flags through the MALL
//  before this dispatch (kernel-boundary ordering). Buffer overwrite safety:
//  producer writes buf[t&1] with h(t+2) only after its step-t+1 poll observed
//  all flags >= t+1, which requires every block to have completed its step-t
//  reads of buf[t&1] (reads are vmcnt-tied before MFMA, publish after S3).
//  wg is XCD-swizzled (xproj/out 64B-line locality, kept from R4/R5).
// ---------------------------------------------------------------------------
__global__ __launch_bounds__(256, 1) void k_recur(
    const __bf16* __restrict__ whhp,
    const float*  __restrict__ xproj,   // [2][32][256][2048]
    const float*  __restrict__ biasm,   // [2][32][2048]
    const float*  __restrict__ cb,      // [32][8]
    const int*    __restrict__ lens,    // [32]
    void* hxch,                         // h exchange region (see above)
    float* __restrict__ out)            // [32][256][1024]
{
  const int tid = threadIdx.x, lane = tid & 63, wv = tid >> 6;
  const int quad = lane >> 4, c16 = lane & 15;
  const int bid = blockIdx.x, dir = bid >> 7;
  const int b7 = bid & 127;
  const int wg = ((b7 & 7) << 4) | (b7 >> 3);   // XCD-aware swizzle
  const int hidx0 = wg * 4;

  char* hd = (char*)hxch;
  char* hdat0 = hd + (size_t)(dir * 2 + 0) * 32768;
  char* hdat1 = hd + (size_t)(dir * 2 + 1) * 32768;
  unsigned* hflag = (unsigned*)(hd + 131072) + dir * 128;

  // basis-weight B fragments -> registers (logical-wg indexed)
  bf16x8 bfrag[4][8];
  {
    const __bf16* base = whhp + (size_t)((dir * 128 + wg) * 4 + wv) * 4 * (8 * 512);
    #pragma unroll
    for (int kt = 0; kt < 4; ++kt)
      #pragma unroll
      for (int n = 0; n < 8; ++n)
        bfrag[kt][n] = *(const bf16x8*)(base + (size_t)(kt * 8 + n) * 512 + lane * 8);
  }
  f32x4 ccv[2][8];
  #pragma unroll
  for (int mt = 0; mt < 2; ++mt)
    #pragma unroll
    for (int n = 0; n < 8; ++n){
      f32x4 v;
      #pragma unroll
      for (int r = 0; r < 4; ++r) v[r] = cb[(mt * 16 + quad * 4 + r) * 8 + n];
      ccv[mt][n] = v;
    }

  const int bb_ = tid >> 2, jj_ = tid & 3;
  float bias_g[4] = {0, 0, 0, 0};
  int mylen = 0;
  float cstate = 0.f;
  if (tid < 128){
    #pragma unroll
    for (int g = 0; g < 4; ++g)
      bias_g[g] = biasm[(size_t)(dir * 32 + bb_) * 2048 + g * 512 + hidx0 + jj_];
    mylen = lens[bb_];
  }

  __shared__ float red[4][2][64][4];
  __shared__ float xg[32][4][4];
  __shared__ float outst[32][4];
  __shared__ __bf16 hbst[32][4];

  // prefetch xproj for step 0 (normal cached load; waves 0-1)
  f32x4 pf = {0, 0, 0, 0};
  const int b_pf = tid >> 2, g_pf = tid & 3;
  if (tid < 128){
    int to0 = dir ? (TT - 1) : 0;
    pf = *(const f32x4*)(xproj + ((size_t)(dir * 32 + b_pf) * TT + to0) * 2048
                         + g_pf * 512 + hidx0);
  }

  // per-lane byte offsets of the 8 bulk-load chunks (p = mt*4 + kt):
  //   kb = (wv*4+kt)*4 + quad, sample = mt*16 + c16  ->  channels
  //   kb*8..kb*8+7 == (wv*4+kt)*32 + quad*8 .. +8 (same as R5 fragment map)
  int hoff[8];
  #pragma unroll
  for (int mt = 0; mt < 2; ++mt)
    #pragma unroll
    for (int kt = 0; kt < 4; ++kt)
      hoff[mt * 4 + kt] = ((((wv * 4 + kt) * 4 + quad) * 32) + mt * 16 + c16) * 16;

  // producer store offset (wave 3, lane s = tid-192): channels wg*4..+3 of
  // sample s live at chunk (wg>>1, s), byte (wg&1)*8 inside it.
  const int pub_off = (((wg >> 1) * 32 + (tid - 192)) << 4) + ((wg & 1) << 3);

  for (int t = 0; t < TT; ++t){
    const int to = dir ? (TT - 1 - t) : t;
    const char* hb = (t & 1) ? hdat1 : hdat0;
    const unsigned tgt = (unsigned)t;

    // ---- poll flags until all 128 wgs have published h(t) ----
    {
      const char* fp = (const char*)hflag + lane * 8;
      while (true){
        u32x2 f = ld_b64_coh(fp);
        asm volatile("s_waitcnt vmcnt(0)" : "+v"(f) :: "memory");
        if (__all((int)(f[0] >= tgt && f[1] >= tgt))) break;
      }
    }

    // ---- bulk-load this wave's quarter of the h state (once) ----
    u32x4 hv[8];
    #pragma unroll
    for (int p = 0; p < 8; ++p)
      hv[p] = ld_b128_coh(hb + hoff[p]);
    asm volatile("s_waitcnt vmcnt(0)"
                 : "+v"(hv[0]), "+v"(hv[1]), "+v"(hv[2]), "+v"(hv[3]),
                   "+v"(hv[4]), "+v"(hv[5]), "+v"(hv[6]), "+v"(hv[7])
                 :: "memory");
    bf16x8 af[2][4];
    #pragma unroll
    for (int p = 0; p < 8; ++p)
      af[p >> 2][p & 3] = __builtin_bit_cast(bf16x8, hv[p]);

    f32x4 acc[8][2];
    #pragma unroll
    for (int n = 0; n < 8; ++n){ acc[n][0] = (f32x4){0,0,0,0}; acc[n][1] = (f32x4){0,0,0,0}; }
    #pragma unroll
    for (int kt = 0; kt < 4; ++kt)
      #pragma unroll
      for (int n = 0; n < 8; ++n){
        acc[n][0] = __builtin_amdgcn_mfma_f32_16x16x32_bf16(af[0][kt], bfrag[kt][n], acc[n][0], 0, 0, 0);
        acc[n][1] = __builtin_amdgcn_mfma_f32_16x16x32_bf16(af[1][kt], bfrag[kt][n], acc[n][1], 0, 0, 0);
      }
    f32x4 mix0 = {0,0,0,0}, mix1 = {0,0,0,0};
    #pragma unroll
    for (int n = 0; n < 8; ++n){
      mix0 += ccv[0][n] * acc[n][0];
      mix1 += ccv[1][n] * acc[n][1];
    }
    *(f32x4*)&red[wv][0][lane][0] = mix0;
    *(f32x4*)&red[wv][1][lane][0] = mix1;
    if (tid < 128)
      *(f32x4*)&xg[b_pf][g_pf][0] = pf;
    __syncthreads();     // S2

    if (tid < 128){
      const int r = bb_ & 15, mt = bb_ >> 4, rg = r & 3, qp = r >> 2;
      float gv[4];
      #pragma unroll
      for (int g = 0; g < 4; ++g){
        int li = qp * 16 + g * 4 + jj_;
        float s = red[0][mt][li][rg] + red[1][mt][li][rg]
                + red[2][mt][li][rg] + red[3][mt][li][rg];
        gv[g] = s + xg[bb_][g][jj_] + bias_g[g];
      }
      float i_ = sigm(gv[0]);
      float f_ = sigm(gv[1]);
      float g_ = tanh_(gv[2]);
      float o_ = sigm(gv[3]);
      bool valid = (to < mylen);
      float cy = valid ? (f_ * cstate + i_ * g_) : 0.f;
      float hy = valid ? (o_ * tanh_(cy)) : 0.f;
      cstate = cy;
      outst[bb_][jj_] = hy;
      hbst[bb_][jj_] = f2bf(hy);
    }
    __syncthreads();     // S3

    // wave 3: publish h slices for step t+1, drain, then raise flag
    if (tid >= 192 && tid < 224){
      int s = tid - 192;
      union { bf16x4 h; u32x2 d; } u;
      u.h = *(bf16x4*)&hbst[s][0];
      char* hn = (t & 1) ? hdat0 : hdat1;
      st_b64_coh(hn + pub_off, u.d);
      asm volatile("s_waitcnt vmcnt(0)" ::: "memory");
      if (s == 0) st_b32_coh(hflag + wg, (unsigned)(t + 1));
    }
    // waves 0-1: prefetch next xproj (cached); wave 2: out store
    if (t < TT - 1 && tid < 128){
      int ton = dir ? (TT - 2 - t) : (t + 1);
      pf = *(const f32x4*)(xproj + ((size_t)(dir * 32 + b_pf) * TT + ton) * 2048
                           + g_pf * 512 + hidx0);
    }
    if (tid >= 128 && tid < 160){
      int s = tid - 128;
      *(f32x4*)(out + ((size_t)s * TT + to) * 1024 + dir * 512 + hidx0)
          = *(f32x4*)&outst[s][0];
    }
  }
}

// ---------------------------------------------------------------------------
extern "C" void kernel_launch(void* const* d_in, const int* in_sizes, int n_in,
                              void* d_out, int out_size, void* d_ws, size_t ws_size,
                              hipStream_t stream)
{
  const float* x      = (const float*)d_in[0];
  const void*  mask   = d_in[1];
  const int*   meta_a = (const int*)d_in[2];
  const int*   meta_c = (const int*)d_in[3];
  const float* emb_a  = (const float*)d_in[4];
  const float* emb_c  = (const float*)d_in[5];
  const float* P_W1   = (const float*)d_in[6];
  const float* P_b1   = (const float*)d_in[7];
  const float* P_W2   = (const float*)d_in[8];
  const float* W_ih   = (const float*)d_in[9];
  const float* W_hh   = (const float*)d_in[10];
  const float* bias_f = (const float*)d_in[11];
  const float* W_ih_r = (const float*)d_in[12];
  const float* W_hh_r = (const float*)d_in[13];
  const float* bias_r = (const float*)d_in[14];
  float* out = (float*)d_out;
  char* ws = (char*)d_ws;

  constexpr size_t OFF_C     = 0;           //   1 KB  c_batch
  constexpr size_t OFF_LEN   = 1024;        //  128 B  lengths
  constexpr size_t OFF_BIAS  = 4096;        //  512 KB mixed biases
  constexpr size_t OFF_H     = 528384;      //  129 KB h data + flags
  constexpr size_t OFF_WHHP  = 790528;      // 33.5 MB basis Whh fragments
  constexpr size_t OFF_XBF   = 34344960;    //  8.4 MB x bf16
  constexpr size_t OFF_WIHM  = 42733568;    //   67 MB mixed Wih (per-dir reuse)
  constexpr size_t OFF_XPROJ = 109842432;   //  134 MB xproj f32 (both dirs)
  constexpr size_t WS_NEED   = 244060160;
  if (ws_size < WS_NEED) return;

  float*   c_b   = (float*)(ws + OFF_C);
  int*     lens  = (int*)(ws + OFF_LEN);
  float*   biasm = (float*)(ws + OFF_BIAS);
  void*    hxch  = (void*)(ws + OFF_H);
  __bf16*  whhp  = (__bf16*)(ws + OFF_WHHP);
  __bf16*  xbf   = (__bf16*)(ws + OFF_XBF);
  __bf16*  wihm  = (__bf16*)(ws + OFF_WIHM);
  float*   xproj = (float*)(ws + OFF_XPROJ);

  k_meta<<<1, 256, 0, stream>>>(mask, meta_a, meta_c, emb_a, emb_c,
                                P_W1, P_b1, P_W2, c_b, lens);
  k_hinit<<<33, 256, 0, stream>>>((u32x4*)hxch);
  k_xbf<<<2048, 256, 0, stream>>>(x, xbf);
  k_whhp<<<8192, 256, 0, stream>>>(W_hh, W_hh_r, whhp);
  k_bias<<<512, 256, 0, stream>>>(bias_f, bias_r, c_b, biasm);
  for (int dir = 0; dir < 2; ++dir){
    k_mixwih<<<512, 256, 0, stream>>>(dir ? W_ih_r : W_ih, c_b, wihm);
    k_gemm<<<1024, 256, 0, stream>>>(xbf, wihm,
                                     xproj + (size_t)dir * 32 * TT * 2048);
  }
  k_recur<<<256, 256, 0, stream>>>(whhp, xproj, biasm, c_b, lens, hxch, out);
}